// Round 7
// baseline (758.317 us; speedup 1.0000x reference)
//
#include <hip/hip_runtime.h>

// out[b, n, k, :] = features[b, topk_indices[b, n, k], :]
// B=32, N=4096, K=20, F=64, fp32.
//
// R6 post-mortem: thrash/MLP/XCD-affinity theories all null. Writes run at
// 3.6 TB/s vs fill's 6.7 on the same buffer. Remaining theory: vmcnt
// load<->store coupling (waitcnt before each store drains prior stores).
// R7: 1-deep software pipeline -- issue next iter's loads BEFORE storing the
// previously loaded value, so stores need no wait and the compiler emits
// counted vmcnt(N). Run `passes`=4 fence-free idempotent passes so the
// dispatch (~600-780us) outranks the 400us poison fills in the top-5 table.

constexpr int B = 32, N = 4096, K = 20, F = 64;
constexpr unsigned NK = (unsigned)N * K;                      // 81,920
constexpr unsigned VEC_PER_ROW = F / 4;                       // 16
constexpr unsigned TOTAL_ROWS = (unsigned)B * NK;             // 2,621,440
constexpr unsigned TOTAL_VEC = TOTAL_ROWS * VEC_PER_ROW;      // 41,943,040

constexpr unsigned BLOCK = 256;
constexpr unsigned GRID = 2048;
constexpr unsigned THREADS = GRID * BLOCK;                    // 524,288
constexpr unsigned ITERS = TOTAL_VEC / THREADS;               // exactly 80
static_assert(ITERS * THREADS == TOTAL_VEC, "exact tiling");

__global__ __launch_bounds__(BLOCK) void gather_rows_kernel(
    const int* __restrict__ idx,      // [B, N, K]
    const float* __restrict__ feat,   // [B, N, F]
    float* __restrict__ out,          // [B, N, K, F]
    int passes)                       // runtime (=4): keeps passes un-collapsed
{
    const unsigned tid0 = blockIdx.x * BLOCK + threadIdx.x;
    const float4* __restrict__ featv = reinterpret_cast<const float4*>(feat);
    float4* __restrict__ outv = reinterpret_cast<float4*>(out);

    for (int p = 0; p < passes; ++p) {
        unsigned i = tid0;
        // prologue: load iteration 0's value
        unsigned row = i >> 4;
        unsigned v   = i & 15u;
        unsigned b   = row / NK;
        int id = idx[row];
        float4 val = featv[(b * (unsigned)N + (unsigned)id) * VEC_PER_ROW + v];

#pragma unroll 1
        for (unsigned j = 0; j < ITERS - 1; ++j) {
            // issue next iteration's loads first...
            unsigned inext = i + THREADS;
            unsigned rown = inext >> 4;
            unsigned vn   = inext & 15u;
            unsigned bn   = rown / NK;
            int idn = idx[rown];
            float4 valn = featv[(bn * (unsigned)N + (unsigned)idn) * VEC_PER_ROW + vn];
            // ...then store the already-in-register value: no wait needed
            outv[i] = val;
            val = valn;
            i = inext;
        }
        outv[i] = val;   // epilogue store
    }
}

extern "C" void kernel_launch(void* const* d_in, const int* in_sizes, int n_in,
                              void* d_out, int out_size, void* d_ws, size_t ws_size,
                              hipStream_t stream) {
    const int*   idx  = (const int*)d_in[0];    // topk_indices [B,N,K] int32
    const float* feat = (const float*)d_in[1];  // features [B,N,F] fp32
    float*       out  = (float*)d_out;          // [B,N,K,F] fp32

    gather_rows_kernel<<<GRID, BLOCK, 0, stream>>>(idx, feat, out, 4);
}